// Round 1
// baseline (22.866 us; speedup 1.0000x reference)
//
#include <hip/hip_runtime.h>

#define NTILE 8
#define THREADS 256

__global__ __launch_bounds__(THREADS, 4) void slayer_exp_kernel(
    const float* __restrict__ batch,      // [B,P,2]
    const float* __restrict__ not_dummy,  // [B,P]
    const float* __restrict__ centers,    // [N,2]
    const float* __restrict__ sharpness,  // [N,2]
    float* __restrict__ out,              // [B,N]
    int B, int P, int N)
{
    const int b   = blockIdx.y;
    const int n0  = blockIdx.x * NTILE;
    const int tid = threadIdx.x;

    const float L2E = 1.4426950408889634f;  // log2(e)

    // Per-center constants: -dist*log2e = A + B*x0 + C*x1 + D*x0^2 + E*x1^2
    float Ac[NTILE], Bc[NTILE], Cc[NTILE], Dc[NTILE], Ec[NTILE];
#pragma unroll
    for (int i = 0; i < NTILE; ++i) {
        int n = n0 + i;
        if (n >= N) n = N - 1;            // clamp (duplicates masked at write)
        float c0 = centers[2 * n + 0];
        float c1 = centers[2 * n + 1];
        float s0 = sharpness[2 * n + 0];
        float s1 = sharpness[2 * n + 1];
        Ac[i] = -(s0 * c0 * c0 + s1 * c1 * c1) * L2E;
        Bc[i] = 2.0f * s0 * c0 * L2E;
        Cc[i] = 2.0f * s1 * c1 * L2E;
        Dc[i] = -s0 * L2E;
        Ec[i] = -s1 * L2E;
    }

    float acc[NTILE];
#pragma unroll
    for (int i = 0; i < NTILE; ++i) acc[i] = 0.0f;

    const float* bb = batch + (size_t)b * P * 2;
    const float* mm = not_dummy + (size_t)b * P;

    // Main loop: 2 points per iteration per thread (float4 = two (x0,x1) pairs)
    const int pairs = P >> 1;
    for (int q = tid; q < pairs; q += THREADS) {
        float4 xy = ((const float4*)bb)[q];
        float2 mk = ((const float2*)mm)[q];
        float x0 = xy.x, x1 = xy.y, y0 = xy.z, y1 = xy.w;
        float xx0 = x0 * x0, xx1 = x1 * x1;
        float yy0 = y0 * y0, yy1 = y1 * y1;
#pragma unroll
        for (int i = 0; i < NTILE; ++i) {
            float t0 = __builtin_fmaf(Bc[i], x0, Ac[i]);
            t0 = __builtin_fmaf(Cc[i], x1, t0);
            t0 = __builtin_fmaf(Dc[i], xx0, t0);
            t0 = __builtin_fmaf(Ec[i], xx1, t0);
            float e0 = __builtin_amdgcn_exp2f(t0);
            acc[i] = __builtin_fmaf(e0, mk.x, acc[i]);

            float t1 = __builtin_fmaf(Bc[i], y0, Ac[i]);
            t1 = __builtin_fmaf(Cc[i], y1, t1);
            t1 = __builtin_fmaf(Dc[i], yy0, t1);
            t1 = __builtin_fmaf(Ec[i], yy1, t1);
            float e1 = __builtin_amdgcn_exp2f(t1);
            acc[i] = __builtin_fmaf(e1, mk.y, acc[i]);
        }
    }

    // Odd-P tail (not hit for P=8192, kept for generality)
    if ((P & 1) && tid == 0) {
        int p = P - 1;
        float x0 = bb[2 * p], x1 = bb[2 * p + 1];
        float m = mm[p];
        float xx0 = x0 * x0, xx1 = x1 * x1;
#pragma unroll
        for (int i = 0; i < NTILE; ++i) {
            float t = __builtin_fmaf(Bc[i], x0, Ac[i]);
            t = __builtin_fmaf(Cc[i], x1, t);
            t = __builtin_fmaf(Dc[i], xx0, t);
            t = __builtin_fmaf(Ec[i], xx1, t);
            acc[i] = __builtin_fmaf(__builtin_amdgcn_exp2f(t), m, acc[i]);
        }
    }

    // Wave-level butterfly reduction (64 lanes), then cross-wave via LDS
#pragma unroll
    for (int i = 0; i < NTILE; ++i) {
        float v = acc[i];
#pragma unroll
        for (int off = 32; off >= 1; off >>= 1)
            v += __shfl_xor(v, off, 64);
        acc[i] = v;
    }

    __shared__ float red[THREADS / 64][NTILE];
    const int wave = tid >> 6;
    const int lane = tid & 63;
    if (lane == 0) {
#pragma unroll
        for (int i = 0; i < NTILE; ++i) red[wave][i] = acc[i];
    }
    __syncthreads();

    if (tid < NTILE && (n0 + tid) < N) {
        float v = 0.0f;
#pragma unroll
        for (int w = 0; w < THREADS / 64; ++w) v += red[w][tid];
        out[(size_t)b * N + n0 + tid] = v;
    }
}

extern "C" void kernel_launch(void* const* d_in, const int* in_sizes, int n_in,
                              void* d_out, int out_size, void* d_ws, size_t ws_size,
                              hipStream_t stream) {
    const float* batch     = (const float*)d_in[0];
    const float* not_dummy = (const float*)d_in[1];
    const float* centers   = (const float*)d_in[2];
    const float* sharp     = (const float*)d_in[3];
    float* out = (float*)d_out;

    const int N  = in_sizes[2] / 2;       // centers: [N,2]
    const int BP = in_sizes[1];           // not_dummy: [B,P]
    const int B  = out_size / N;          // out: [B,N]
    const int P  = BP / B;

    dim3 grid((N + NTILE - 1) / NTILE, B);
    slayer_exp_kernel<<<grid, THREADS, 0, stream>>>(batch, not_dummy, centers, sharp,
                                                    out, B, P, N);
}

// Round 2
// 21.343 us; speedup vs baseline: 1.0713x; 1.0713x over previous
//
#include <hip/hip_runtime.h>

typedef float v2f __attribute__((ext_vector_type(2)));

#define NTILE 8            // centers per block
#define NPAIR (NTILE / 2)  // packed center pairs
#define THREADS 256

__global__ __launch_bounds__(THREADS, 4) void slayer_exp_kernel(
    const float* __restrict__ batch,      // [B,P,2]
    const float* __restrict__ not_dummy,  // [B,P]
    const float* __restrict__ centers,    // [N,2]
    const float* __restrict__ sharpness,  // [N,2]
    float* __restrict__ out,              // [B,N]
    int B, int P, int N)
{
    const int b   = blockIdx.y;
    const int n0  = blockIdx.x * NTILE;
    const int tid = threadIdx.x;

    const float L2E = 1.4426950408889634f;  // log2(e)

    // Per-center constants, packed across center PAIRS so v_pk_fma_f32 sources
    // are natural register pairs (no splat duplication for the 40 constants):
    // -dist*log2e = A + B*x0 + C*x1 + D*x0^2 + E*x1^2
    v2f Av[NPAIR], Bv[NPAIR], Cv[NPAIR], Dv[NPAIR], Ev[NPAIR];
#pragma unroll
    for (int i = 0; i < NPAIR; ++i) {
#pragma unroll
        for (int h = 0; h < 2; ++h) {
            int n = n0 + 2 * i + h;
            if (n >= N) n = N - 1;  // clamp; duplicates masked at write
            float c0 = centers[2 * n + 0];
            float c1 = centers[2 * n + 1];
            float s0 = sharpness[2 * n + 0];
            float s1 = sharpness[2 * n + 1];
            Av[i][h] = -(s0 * c0 * c0 + s1 * c1 * c1) * L2E;
            Bv[i][h] = 2.0f * s0 * c0 * L2E;
            Cv[i][h] = 2.0f * s1 * c1 * L2E;
            Dv[i][h] = -s0 * L2E;
            Ev[i][h] = -s1 * L2E;
        }
    }

    v2f acc[NPAIR];
#pragma unroll
    for (int i = 0; i < NPAIR; ++i) acc[i] = (v2f){0.0f, 0.0f};

    const float4* B4 = (const float4*)(batch + (size_t)b * P * 2);  // 2 pts per float4
    const float4* M4 = (const float4*)(not_dummy + (size_t)b * P);  // 4 masks per float4

    // Main loop: 4 points (one "quad") per thread per iteration, register
    // double-buffered so next iteration's loads are in flight under compute.
    const int quads = P >> 2;
    int q = tid;
    bool valid = q < quads;
    float4 pa, pb, pm;
    if (valid) { pa = B4[2 * q]; pb = B4[2 * q + 1]; pm = M4[q]; }

    while (valid) {
        const int qn = q + THREADS;
        const bool vn = qn < quads;
        float4 na, nb, nm;
        if (vn) { na = B4[2 * qn]; nb = B4[2 * qn + 1]; nm = M4[qn]; }

        const float px0[4] = {pa.x, pa.z, pb.x, pb.z};  // coord-0 of the 4 points
        const float px1[4] = {pa.y, pa.w, pb.y, pb.w};  // coord-1
        const float pmk[4] = {pm.x, pm.y, pm.z, pm.w};

#pragma unroll
        for (int p = 0; p < 4; ++p) {
            const v2f sx0 = {px0[p], px0[p]};
            const v2f sx1 = {px1[p], px1[p]};
            const v2f sq0 = sx0 * sx0;
            const v2f sq1 = sx1 * sx1;
            const v2f smk = {pmk[p], pmk[p]};
#pragma unroll
            for (int i = 0; i < NPAIR; ++i) {
                v2f t = __builtin_elementwise_fma(Bv[i], sx0, Av[i]);
                t = __builtin_elementwise_fma(Cv[i], sx1, t);
                t = __builtin_elementwise_fma(Dv[i], sq0, t);
                t = __builtin_elementwise_fma(Ev[i], sq1, t);
                v2f e;
                e.x = __builtin_amdgcn_exp2f(t.x);
                e.y = __builtin_amdgcn_exp2f(t.y);
                acc[i] = __builtin_elementwise_fma(e, smk, acc[i]);
            }
        }

        q = qn; valid = vn; pa = na; pb = nb; pm = nm;
    }

    // Tail: P % 4 leftover points (not hit for P=8192), thread 0 only.
    if ((P & 3) && tid == 0) {
        const float* bb = batch + (size_t)b * P * 2;
        const float* mm = not_dummy + (size_t)b * P;
        for (int p = quads << 2; p < P; ++p) {
            float x0 = bb[2 * p], x1 = bb[2 * p + 1], m = mm[p];
            v2f sx0 = {x0, x0}, sx1 = {x1, x1};
            v2f sq0 = sx0 * sx0, sq1 = sx1 * sx1, smk = {m, m};
#pragma unroll
            for (int i = 0; i < NPAIR; ++i) {
                v2f t = __builtin_elementwise_fma(Bv[i], sx0, Av[i]);
                t = __builtin_elementwise_fma(Cv[i], sx1, t);
                t = __builtin_elementwise_fma(Dv[i], sq0, t);
                t = __builtin_elementwise_fma(Ev[i], sq1, t);
                v2f e;
                e.x = __builtin_amdgcn_exp2f(t.x);
                e.y = __builtin_amdgcn_exp2f(t.y);
                acc[i] = __builtin_elementwise_fma(e, smk, acc[i]);
            }
        }
    }

    // Wave-level butterfly reduction (64 lanes), then cross-wave via LDS.
    float red8[NTILE];
#pragma unroll
    for (int i = 0; i < NPAIR; ++i) { red8[2 * i] = acc[i].x; red8[2 * i + 1] = acc[i].y; }
#pragma unroll
    for (int i = 0; i < NTILE; ++i) {
        float v = red8[i];
#pragma unroll
        for (int off = 32; off >= 1; off >>= 1)
            v += __shfl_xor(v, off, 64);
        red8[i] = v;
    }

    __shared__ float red[THREADS / 64][NTILE];
    const int wave = tid >> 6;
    const int lane = tid & 63;
    if (lane == 0) {
#pragma unroll
        for (int i = 0; i < NTILE; ++i) red[wave][i] = red8[i];
    }
    __syncthreads();

    if (tid < NTILE && (n0 + tid) < N) {
        float v = 0.0f;
#pragma unroll
        for (int w = 0; w < THREADS / 64; ++w) v += red[w][tid];
        out[(size_t)b * N + n0 + tid] = v;
    }
}

extern "C" void kernel_launch(void* const* d_in, const int* in_sizes, int n_in,
                              void* d_out, int out_size, void* d_ws, size_t ws_size,
                              hipStream_t stream) {
    const float* batch     = (const float*)d_in[0];
    const float* not_dummy = (const float*)d_in[1];
    const float* centers   = (const float*)d_in[2];
    const float* sharp     = (const float*)d_in[3];
    float* out = (float*)d_out;

    const int N  = in_sizes[2] / 2;       // centers: [N,2]
    const int BP = in_sizes[1];           // not_dummy: [B,P]
    const int B  = out_size / N;          // out: [B,N]
    const int P  = BP / B;

    dim3 grid((N + NTILE - 1) / NTILE, B);
    slayer_exp_kernel<<<grid, THREADS, 0, stream>>>(batch, not_dummy, centers, sharp,
                                                    out, B, P, N);
}

// Round 3
// 20.026 us; speedup vs baseline: 1.1418x; 1.0658x over previous
//
#include <hip/hip_runtime.h>

typedef float v2f __attribute__((ext_vector_type(2)));

#define NTILE 8            // centers per block
#define NPAIR (NTILE / 2)  // packed center pairs
#define THREADS 256

// Forced VOP3P packed fp32 ops (clang won't reliably form these from vector IR)
static __device__ __forceinline__ v2f pk_fma(v2f a, v2f b, v2f c) {
    v2f d;
    asm("v_pk_fma_f32 %0, %1, %2, %3" : "=v"(d) : "v"(a), "v"(b), "v"(c));
    return d;
}
static __device__ __forceinline__ v2f pk_mul(v2f a, v2f b) {
    v2f d;
    asm("v_pk_mul_f32 %0, %1, %2" : "=v"(d) : "v"(a), "v"(b));
    return d;
}

// Schraudolph fast exp2 on the pre-scaled domain: y = bitcast((int)u).
// u = BIAS + 2^23 * t, t = log2 of desired result (t <= 0 here).
static __device__ __forceinline__ v2f fast_exp_pair(v2f u) {
    v2f r;
    r.x = __int_as_float((int)u.x);
    r.y = __int_as_float((int)u.y);
    return r;
}

__global__ __launch_bounds__(THREADS, 4) void slayer_exp_kernel(
    const float* __restrict__ batch,      // [B,P,2]
    const float* __restrict__ not_dummy,  // [B,P]
    const float* __restrict__ centers,    // [N,2]
    const float* __restrict__ sharpness,  // [N,2]
    float* __restrict__ out,              // [B,N]
    int B, int P, int N)
{
    const int b   = blockIdx.y;
    const int n0  = blockIdx.x * NTILE;
    const int tid = threadIdx.x;

    // exp(-dist) = 2^t, t = -dist*log2e. Schraudolph: y = bitcast((int)(2^23*t + BIAS))
    // BIAS = 127*2^23 - 480667 (mean-centered: zero-mean log-error over fract)
    const float S    = 12102203.161561485f;  // 2^23 * log2(e)
    const float BIAS = 1064872549.0f;

    // Per-center-pair packed constants:
    // u = A + B*x0 + C*x1 + D*x0^2 + E*x1^2   (already scaled by S, biased)
    v2f Av[NPAIR], Bv[NPAIR], Cv[NPAIR], Dv[NPAIR], Ev[NPAIR];
#pragma unroll
    for (int i = 0; i < NPAIR; ++i) {
#pragma unroll
        for (int h = 0; h < 2; ++h) {
            int n = n0 + 2 * i + h;
            if (n >= N) n = N - 1;  // clamp; duplicates masked at write
            float c0 = centers[2 * n + 0];
            float c1 = centers[2 * n + 1];
            float s0 = sharpness[2 * n + 0];
            float s1 = sharpness[2 * n + 1];
            Av[i][h] = BIAS - S * (s0 * c0 * c0 + s1 * c1 * c1);
            Bv[i][h] = S * 2.0f * s0 * c0;
            Cv[i][h] = S * 2.0f * s1 * c1;
            Dv[i][h] = -S * s0;
            Ev[i][h] = -S * s1;
        }
    }

    v2f acc[NPAIR];
#pragma unroll
    for (int i = 0; i < NPAIR; ++i) acc[i] = (v2f){0.0f, 0.0f};

    const float4* B4 = (const float4*)(batch + (size_t)b * P * 2);  // 2 pts per float4
    const float4* M4 = (const float4*)(not_dummy + (size_t)b * P);  // 4 masks per float4

    // Main loop: 4 points per thread per iteration, register double-buffered.
    const int quads = P >> 2;
    int q = tid;
    bool valid = q < quads;
    float4 pa, pb, pm;
    if (valid) { pa = B4[2 * q]; pb = B4[2 * q + 1]; pm = M4[q]; }

    while (valid) {
        const int qn = q + THREADS;
        const bool vn = qn < quads;
        float4 na, nb, nm;
        if (vn) { na = B4[2 * qn]; nb = B4[2 * qn + 1]; nm = M4[qn]; }

        const float px0[4] = {pa.x, pa.z, pb.x, pb.z};
        const float px1[4] = {pa.y, pa.w, pb.y, pb.w};
        const float pmk[4] = {pm.x, pm.y, pm.z, pm.w};

#pragma unroll
        for (int p = 0; p < 4; ++p) {
            const v2f sx0 = {px0[p], px0[p]};
            const v2f sx1 = {px1[p], px1[p]};
            const v2f smk = {pmk[p], pmk[p]};
            const v2f sq0 = pk_mul(sx0, sx0);
            const v2f sq1 = pk_mul(sx1, sx1);
#pragma unroll
            for (int i = 0; i < NPAIR; ++i) {
                v2f t = pk_fma(Bv[i], sx0, Av[i]);
                t = pk_fma(Cv[i], sx1, t);
                t = pk_fma(Dv[i], sq0, t);
                t = pk_fma(Ev[i], sq1, t);
                acc[i] = pk_fma(fast_exp_pair(t), smk, acc[i]);
            }
        }

        q = qn; valid = vn; pa = na; pb = nb; pm = nm;
    }

    // Tail: P % 4 leftover points (not hit for P=8192), thread 0 only.
    if ((P & 3) && tid == 0) {
        const float* bb = batch + (size_t)b * P * 2;
        const float* mm = not_dummy + (size_t)b * P;
        for (int p = quads << 2; p < P; ++p) {
            float x0 = bb[2 * p], x1 = bb[2 * p + 1], m = mm[p];
            v2f sx0 = {x0, x0}, sx1 = {x1, x1}, smk = {m, m};
            v2f sq0 = pk_mul(sx0, sx0), sq1 = pk_mul(sx1, sx1);
#pragma unroll
            for (int i = 0; i < NPAIR; ++i) {
                v2f t = pk_fma(Bv[i], sx0, Av[i]);
                t = pk_fma(Cv[i], sx1, t);
                t = pk_fma(Dv[i], sq0, t);
                t = pk_fma(Ev[i], sq1, t);
                acc[i] = pk_fma(fast_exp_pair(t), smk, acc[i]);
            }
        }
    }

    // Wave-level butterfly reduction (64 lanes), then cross-wave via LDS.
    float red8[NTILE];
#pragma unroll
    for (int i = 0; i < NPAIR; ++i) { red8[2 * i] = acc[i].x; red8[2 * i + 1] = acc[i].y; }
#pragma unroll
    for (int i = 0; i < NTILE; ++i) {
        float v = red8[i];
#pragma unroll
        for (int off = 32; off >= 1; off >>= 1)
            v += __shfl_xor(v, off, 64);
        red8[i] = v;
    }

    __shared__ float red[THREADS / 64][NTILE];
    const int wave = tid >> 6;
    const int lane = tid & 63;
    if (lane == 0) {
#pragma unroll
        for (int i = 0; i < NTILE; ++i) red[wave][i] = red8[i];
    }
    __syncthreads();

    if (tid < NTILE && (n0 + tid) < N) {
        float v = 0.0f;
#pragma unroll
        for (int w = 0; w < THREADS / 64; ++w) v += red[w][tid];
        out[(size_t)b * N + n0 + tid] = v;
    }
}

extern "C" void kernel_launch(void* const* d_in, const int* in_sizes, int n_in,
                              void* d_out, int out_size, void* d_ws, size_t ws_size,
                              hipStream_t stream) {
    const float* batch     = (const float*)d_in[0];
    const float* not_dummy = (const float*)d_in[1];
    const float* centers   = (const float*)d_in[2];
    const float* sharp     = (const float*)d_in[3];
    float* out = (float*)d_out;

    const int N  = in_sizes[2] / 2;       // centers: [N,2]
    const int BP = in_sizes[1];           // not_dummy: [B,P]
    const int B  = out_size / N;          // out: [B,N]
    const int P  = BP / B;

    dim3 grid((N + NTILE - 1) / NTILE, B);
    slayer_exp_kernel<<<grid, THREADS, 0, stream>>>(batch, not_dummy, centers, sharp,
                                                    out, B, P, N);
}